// Round 20
// baseline (23.842 us; speedup 1.0000x reference)
//
#include <hip/hip_runtime.h>

// out[n,k] = sum_{i,j} x[n,i] * W[k,i,j] * x[n,j]   (N=262144 rows, D=32)
// R20 vs R17/R19 (22.8us twins): 2-CHUNK SOFTWARE PIPELINE, lean point.
// R19 proved LDS-pipe and occupancy trade off to zero; remaining gap is the
// load->compute->drain phase serialization (2 blocks/CU, same phase). Here:
// block = 512 rows = 2 chunks x 256; both chunks' x loads issued up front;
// ONE btab copy per 512 rows (R17 amortization, which R18 lost); stage both
// chunks (two 18KB buffers); ONE barrier; then chunk0 {ypk,K-loop,nt-store}
// then chunk1 -- chunk0's 16.7MB drain overlaps chunk1's compute, waves
// free-run after the single barrier. 1-tile K-loop (~60 regs), (512,4),
// LDS 69.7KB -> 2 blocks/CU. Math identical (absmax 0.25).
//
// Algorithm: symmetrized circular-diagonal GEMM. p = d*32+i, d=0..16,
// z[n,p] = x[n,i]*x[n,(i+d)&31], Wf[p,k] = W[k,i,j]+W[k,j,i] (d=0 diag,
// d=16 half), K = 528 = 33 MFMA steps of v_mfma_f32_32x32x16_f16.

typedef _Float16 f16x2 __attribute__((ext_vector_type(2)));
typedef _Float16 f16x4 __attribute__((ext_vector_type(4)));
typedef _Float16 f16x8 __attribute__((ext_vector_type(8)));
typedef float    f32x16 __attribute__((ext_vector_type(16)));

static __device__ __forceinline__ unsigned int pk2_f16(float lo, float hi) {
    return __builtin_bit_cast(unsigned int, __builtin_amdgcn_cvt_pkrtz(lo, hi));
}
static __device__ __forceinline__ f16x2 u2h(unsigned int u) {
    return __builtin_bit_cast(f16x2, u);
}
static __device__ __forceinline__ unsigned short f16b(float f) {
    _Float16 h = (_Float16)f;
    return __builtin_bit_cast(unsigned short, h);
}

// ---- prep (R16): one block per k; stage W_k in LDS coalesced, gather ----
__global__ __launch_bounds__(256)
void prep_btab_sym(const float* __restrict__ W, unsigned short* __restrict__ bt) {
    __shared__ float Wlds[1024];                    // 4 KiB = W[k,:,:]
    const int k = blockIdx.x;                       // 0..31
    const int t = threadIdx.x;
    {
        const float4* src = (const float4*)(W + k * 1024);
        ((float4*)Wlds)[t] = src[t];
    }
    __syncthreads();
    if (t < 66) {                                   // 33 n x 2 l-halves
        int n  = t >> 1;
        int lh = t & 1;                             // l = k + lh*32
        int d  = (n == 32) ? 16 : (n >> 1);
        int q  = (n == 32) ? 0  : (n & 1);
        unsigned short v[8];
        #pragma unroll
        for (int b = 0; b < 8; ++b) {
            int i = q * 16 + lh * 8 + b;
            int j = (i + d) & 31;
            float s = (d == 0) ? Wlds[i * 32 + i]
                               : Wlds[i * 32 + j] + Wlds[j * 32 + i];
            v[b] = f16b(s);
        }
        uint4 pk;
        pk.x = (unsigned int)v[0] | ((unsigned int)v[1] << 16);
        pk.y = (unsigned int)v[2] | ((unsigned int)v[3] << 16);
        pk.z = (unsigned int)v[4] | ((unsigned int)v[5] << 16);
        pk.w = (unsigned int)v[6] | ((unsigned int)v[7] << 16);
        ((uint4*)bt)[n * 64 + k + lh * 32] = pk;
    }
}

#define XS 18   // u32 per staged row: gcd(18,32)=2 -> 2-way read aliasing (free)

// one K-loop + store for a chunk; YSTAGE = that chunk's stage base,
// WROW = first row of this wave's tile in the chunk. SSA-pure body.
#define CHUNK_COMPUTE(YSTAGE, WROW)                                              \
    {                                                                            \
        unsigned int ypk[16];                                                    \
        {                                                                        \
            unsigned int xpk[16];                                                \
            const unsigned int* xr = &(YSTAGE)[(wave * 32 + rl) * XS];           \
            _Pragma("unroll")                                                    \
            for (int c = 0; c < 4; ++c) {                                        \
                uint4 v = *(const uint4*)(xr + c * 4);                           \
                xpk[c * 4 + 0] = v.x; xpk[c * 4 + 1] = v.y;                      \
                xpk[c * 4 + 2] = v.z; xpk[c * 4 + 3] = v.w;                      \
            }                                                                    \
            _Pragma("unroll")                                                    \
            for (int c = 0; c < 16; ++c)                                         \
                ypk[c] = hi ? xpk[(c + 4) & 15] : xpk[c];                        \
        }                                                                        \
        f32x16 acc;                                                              \
        _Pragma("unroll")                                                        \
        for (int e = 0; e < 16; ++e) acc[e] = 0.0f;                              \
        _Pragma("unroll")                                                        \
        for (int s = 0; s < 33; ++s) {                                           \
            const int d   = (s == 32) ? 16 : (s >> 1);                           \
            const int q8  = ((s == 32) ? 0 : (s & 1)) * 8;                       \
            const int dh  = d >> 1;                                              \
            const bool od = (d & 1) != 0;                                        \
            f16x8 bfrag = *(const f16x8*)(&btab[(s * 64 + lane) * 8]);           \
            f16x2 b0 = od ? u2h(__builtin_amdgcn_perm(ypk[(q8 + 0 + dh + 1) & 15], ypk[(q8 + 0 + dh) & 15], 0x05040302u)) : u2h(ypk[(q8 + 0 + dh) & 15]); \
            f16x2 b1 = od ? u2h(__builtin_amdgcn_perm(ypk[(q8 + 1 + dh + 1) & 15], ypk[(q8 + 1 + dh) & 15], 0x05040302u)) : u2h(ypk[(q8 + 1 + dh) & 15]); \
            f16x2 b2 = od ? u2h(__builtin_amdgcn_perm(ypk[(q8 + 2 + dh + 1) & 15], ypk[(q8 + 2 + dh) & 15], 0x05040302u)) : u2h(ypk[(q8 + 2 + dh) & 15]); \
            f16x2 b3 = od ? u2h(__builtin_amdgcn_perm(ypk[(q8 + 3 + dh + 1) & 15], ypk[(q8 + 3 + dh) & 15], 0x05040302u)) : u2h(ypk[(q8 + 3 + dh) & 15]); \
            f16x2 a0 = u2h(ypk[q8 + 0]) * b0;                                    \
            f16x2 a1 = u2h(ypk[q8 + 1]) * b1;                                    \
            f16x2 a2 = u2h(ypk[q8 + 2]) * b2;                                    \
            f16x2 a3 = u2h(ypk[q8 + 3]) * b3;                                    \
            f16x4 lo = __builtin_shufflevector(a0, a1, 0, 1, 2, 3);              \
            f16x4 hf = __builtin_shufflevector(a2, a3, 0, 1, 2, 3);              \
            f16x8 a  = __builtin_shufflevector(lo, hf, 0, 1, 2, 3, 4, 5, 6, 7);  \
            acc = __builtin_amdgcn_mfma_f32_32x32x16_f16(a, bfrag, acc, 0, 0, 0);\
        }                                                                        \
        float* ob = out + ((WROW) + 4 * hi) * 32 + rl;                           \
        _Pragma("unroll")                                                        \
        for (int e = 0; e < 16; ++e)                                             \
            __builtin_nontemporal_store(acc[e], ob + (e & 3) * 32 + (e >> 2) * 256); \
    }

__global__ __launch_bounds__(512, 4)
void quadform_kernel(const float* __restrict__ x,
                     const unsigned short* __restrict__ bt_ws,
                     float* __restrict__ out) {
    __shared__ __align__(16) unsigned short btab[33 * 64 * 8];      // 33792 B
    __shared__ __align__(16) unsigned int   xstage0[256 * XS];      // 18432 B
    __shared__ __align__(16) unsigned int   xstage1[256 * XS];      // 18432 B

    const int tid  = threadIdx.x;
    const int lane = tid & 63;
    const int wave = tid >> 6;
    const int hi   = lane >> 5;
    const int rl   = lane & 31;
    const long blockrow = (long)blockIdx.x * 512;

    // ---- 1) issue BOTH chunks' coalesced x loads (HBM-longest first) ----
    const float4* xsrc = (const float4*)(x + blockrow * 32);
    float4 xg0 = xsrc[tid];
    float4 xg1 = xsrc[512 + tid];
    float4 xg2 = xsrc[1024 + tid];
    float4 xg3 = xsrc[1536 + tid];
    float4 xg4 = xsrc[2048 + tid];
    float4 xg5 = xsrc[2560 + tid];
    float4 xg6 = xsrc[3072 + tid];
    float4 xg7 = xsrc[3584 + tid];

    // ---- 2) one btab copy per 512 rows (L2-resident source) ----
    const uint4* bsrc = (const uint4*)bt_ws;
    uint4* bdst = (uint4*)btab;
    {
        uint4 b0 = bsrc[tid];
        uint4 b1 = bsrc[512 + tid];
        uint4 b2 = bsrc[1024 + tid];
        uint4 b3 = bsrc[1536 + tid];
        bdst[tid]        = b0;
        bdst[512 + tid]  = b1;
        bdst[1024 + tid] = b2;
        bdst[1536 + tid] = b3;
        if (tid < 64) bdst[2048 + tid] = bsrc[2048 + tid];
    }

    // ---- 3) pack + stage chunk0 then chunk1 (loads consumed here) ----
    #pragma unroll
    for (int c = 0; c < 4; ++c) {
        float4 v = (c == 0) ? xg0 : (c == 1) ? xg1 : (c == 2) ? xg2 : xg3;
        int idx = c * 512 + tid;
        int row = idx >> 3;
        int sub = idx & 7;
        uint2 w2;
        w2.x = pk2_f16(v.x, v.y);
        w2.y = pk2_f16(v.z, v.w);
        *(uint2*)&xstage0[row * XS + sub * 2] = w2;
    }
    #pragma unroll
    for (int c = 0; c < 4; ++c) {
        float4 v = (c == 0) ? xg4 : (c == 1) ? xg5 : (c == 2) ? xg6 : xg7;
        int idx = c * 512 + tid;
        int row = idx >> 3;
        int sub = idx & 7;
        uint2 w2;
        w2.x = pk2_f16(v.x, v.y);
        w2.y = pk2_f16(v.z, v.w);
        *(uint2*)&xstage1[row * XS + sub * 2] = w2;
    }
    __syncthreads();   // the ONLY barrier

    // ---- 4) chunk0: compute + store (drain overlaps chunk1 compute) ----
    CHUNK_COMPUTE(xstage0, blockrow + wave * 32)
    // ---- 5) chunk1 ----
    CHUNK_COMPUTE(xstage1, blockrow + 256 + wave * 32)
}

extern "C" void kernel_launch(void* const* d_in, const int* in_sizes, int n_in,
                              void* d_out, int out_size, void* d_ws, size_t ws_size,
                              hipStream_t stream) {
    const float* x = (const float*)d_in[0];
    const float* W = (const float*)d_in[1];
    float* out = (float*)d_out;
    unsigned short* bt = (unsigned short*)d_ws;    // 33 KiB table

    prep_btab_sym<<<32, 256, 0, stream>>>(W, bt);
    int nrows = in_sizes[0] / 32;          // 262144
    int grid  = nrows / 512;               // 512 blocks x 512 thr, 2 chunks
    quadform_kernel<<<grid, 512, 0, stream>>>(x, bt, out);
}